// Round 10
// baseline (898.272 us; speedup 1.0000x reference)
//
#include <hip/hip_runtime.h>

// SVSAlgorithm: per-pixel sequential threshold recurrence over T frames,
// fused with 3x3 constant-kernel "DiffErosion" conv + relu epilogue.
//
// Merged producer/consumer, attempt #3 (R5/R8 failures root-caused):
//  - scan role (blocks 0..79, 256 thr, 1 chain/thread): R2-proven 2x32
//    double-buffered prefetch, each issue block pinned with
//    sched_barrier(0) -- R9 proved this stops the compiler sinking the
//    prefetch loads (the R5/R8 collapse mechanism). Snapshots every 64
//    frames stored fence-free; release (syncthreads + thread0 threadfence
//    [L2 writeback for cross-XCD visibility] + flag atomicAdd) only every
//    4 snapshots -> 8 vmcnt drains per scan instead of 31.
//  - compute role (blocks 80..3919): R9-proven compute<64> body. Slice-
//    major order (early-resident blocks need early snapshots); XCD chunk
//    within slice for output-line L2 merging. Slice 0 starts immediately;
//    slice k>0 spins (thread 0, s_sleep, 2ms timeout) on group flag
//    (g=(k-1)>>2) == 80, timeout -> bit-exact self-warm-up fallback ->
//    correct under ANY dispatch order (protocol passed correctness in
//    R5+R8 even when slow).
//  - __launch_bounds__(256,1): VGPR budget 512 so the scan path's ~80-100
//    live regs allocate without spill; compute occupancy then ~5 blocks/CU
//    (>= the 4.7 avg measured in R9's standalone compute).
//  - compute math: sigmoid via exp2(fma)+v_rcp; conv == box-sum (all 9
//    weights equal): vertical = 2 LDS reads + own reg, horizontal via DPP
//    row_shr/row_shl; LDS sm[row][frame][col], row stride 136 == 8 mod 32
//    banks -> <=2-way. State updates replicate reference f32 op order.
//  ws ladder: merged (5.08MB+128) -> two-launch SNAP=64 -> SNAP=128 ->
//  single-slice recompute.

#define TILE_W 16
#define TILE_H 16
#define IN_W 14
#define IN_H 14
#define BUF 8        // frames per LDS stage in compute role
#define PRE 32       // scan prefetch half-depth (double buffer)

constexpr int T_FRAMES = 2048;
constexpr int H_IMG = 128;
constexpr int W_IMG = 160;
constexpr int HW = H_IMG * W_IMG;
constexpr int SNAP = 64;
constexpr int NSLICE = T_FRAMES / SNAP;          // 32
constexpr int NSNAP = NSLICE - 1;                // 31 snapshots, k=0..30
constexpr int TEFF = T_FRAMES - SNAP;            // 1984: frames beyond are never consumed
constexpr int SCAN_BLOCKS = HW / 256;            // 80
constexpr int NTILE = 120;
constexpr int COMPUTE_BLOCKS = NTILE * NSLICE;   // 3840
constexpr size_t FLAGS_BYTES = 128;              // 8 group flags
constexpr size_t WS_MERGED = FLAGS_BYTES + (size_t)NSNAP * HW * sizeof(float2);
constexpr float C1 = 721.3475204444817f;         // 500 * log2(e)
constexpr unsigned long long SPIN_TIMEOUT = 200000ull;  // ~2ms @100MHz realtime

constexpr size_t ws_needed(int snap) {
    return (size_t)(T_FRAMES / snap - 1) * HW * sizeof(float2);
}

__device__ __forceinline__ float dpp_from_left(float v) {   // lane n <- lane n-1 (16-lane rows)
    return __int_as_float(__builtin_amdgcn_update_dpp(0, __float_as_int(v), 0x111, 0xF, 0xF, true));
}
__device__ __forceinline__ float dpp_from_right(float v) {  // lane n <- lane n+1
    return __int_as_float(__builtin_amdgcn_update_dpp(0, __float_as_int(v), 0x101, 0xF, 0xF, true));
}

// ---------------- merged producer/consumer kernel -------------------------
__global__ __launch_bounds__(256, 1)
void svs_pc(const float* __restrict__ x, const float* __restrict__ params,
            const float* __restrict__ HT0, const float* __restrict__ LT0,
            const float* __restrict__ kern,
            float2* __restrict__ snap, int* __restrict__ flags,
            float* __restrict__ out)
{
    const float dC = params[0];
    const float dO = params[1];

    if (blockIdx.x < SCAN_BLOCKS) {
        // ------------- scan role: pinned double-buffer ---------------
        const int pix = (int)blockIdx.x * 256 + (int)threadIdx.x;
        float HT = HT0[pix];
        float LT = LT0[pix];
        const float* xp = x + pix;

        float va[PRE], vb[PRE];
        #pragma unroll
        for (int i = 0; i < PRE; ++i) va[i] = xp[i * HW];
        __builtin_amdgcn_sched_barrier(0);

        for (int t = 0; t < TEFF; t += 2 * PRE) {   // 2*PRE == SNAP == 64
            #pragma unroll
            for (int i = 0; i < PRE; ++i) vb[i] = xp[(t + PRE + i) * HW];
            __builtin_amdgcn_sched_barrier(0);
            #pragma unroll
            for (int i = 0; i < PRE; ++i) {
                const float img = va[i];
                HT = ((img - HT) > 0.0f) ? (HT + dO) : (HT - dC);
                LT = ((LT - img) > 0.0f) ? (LT - dO) : (LT + dC);
            }
            if (t + 2 * PRE < TEFF) {
                #pragma unroll
                for (int i = 0; i < PRE; ++i) va[i] = xp[(t + 2 * PRE + i) * HW];
            }
            __builtin_amdgcn_sched_barrier(0);
            #pragma unroll
            for (int i = 0; i < PRE; ++i) {
                const float img = vb[i];
                HT = ((img - HT) > 0.0f) ? (HT + dO) : (HT - dC);
                LT = ((LT - img) > 0.0f) ? (LT - dO) : (LT + dC);
            }
            // state = after frame t+63; snapshot k consumed by slice k+1
            const int k = t / SNAP;                 // 0..30
            snap[(size_t)k * HW + pix] = make_float2(HT, LT);
            // grouped release: post group g=k>>2 when its last snapshot lands
            if ((k & 3) == 3 || k == NSNAP - 1) {
                __syncthreads();                    // all block stores issued/acked
                if (threadIdx.x == 0) {
                    __threadfence();                // L2 writeback: cross-XCD visible
                    __atomic_fetch_add(&flags[k >> 2], 1, __ATOMIC_RELAXED);
                }
            }
        }
        return;
    }

    // ------------- compute role ----------------
    const int cb = (int)blockIdx.x - SCAN_BLOCKS;
    const int slice = cb / NTILE;                 // slice-major
    const int c  = cb % NTILE;
    const int w  = (c & 7) * 15 + (c >> 3);       // XCD chunk within slice
    const int bx = w % 12;
    const int by = w / 12;

    const int tx = threadIdx.x & 15;
    const int ty = threadIdx.x >> 4;
    const int gx = bx * IN_W + tx - 1;
    const int gy = by * IN_H + ty - 1;
    const int t0 = slice * SNAP;

    const bool valid = (gx >= 0) & (gx < W_IMG) & (gy >= 0) & (gy < H_IMG);
    const int cx = min(max(gx, 0), W_IMG - 1);
    const int cy = min(max(gy, 0), H_IMG - 1);
    const int pix = cy * W_IMG + cx;

    const float dHot = params[2];
    const float kw   = kern[4];        // all 9 weights equal (2/9)
    const float c0   = dHot * C1;      // exp2 arg = fma(a, -C1, c0)
    const float* xp  = x + pix;
    float* op = out + pix;

    __shared__ float sm[TILE_H][BUF][TILE_W + 1];
    __shared__ int sReady;

    float HT, LT;
    if (slice == 0) {
        HT = valid ? HT0[pix] : 0.0f;
        LT = valid ? LT0[pix] : 0.0f;
    } else {
        const int g = (slice - 1) >> 2;
        if (threadIdx.x == 0) {
            int got = __atomic_load_n(&flags[g], __ATOMIC_RELAXED);
            if (got < SCAN_BLOCKS) {
                const unsigned long long ts = __builtin_amdgcn_s_memrealtime();
                do {
                    __builtin_amdgcn_s_sleep(32);
                    got = __atomic_load_n(&flags[g], __ATOMIC_RELAXED);
                } while (got < SCAN_BLOCKS &&
                         (__builtin_amdgcn_s_memrealtime() - ts) < SPIN_TIMEOUT);
            }
            sReady = (got >= SCAN_BLOCKS) ? 1 : 0;
        }
        __syncthreads();
        if (sReady) {
            __threadfence();                      // acquire side
            const float2 s = snap[(size_t)(slice - 1) * HW + pix];
            HT = valid ? s.x : 0.0f;
            LT = valid ? s.y : 0.0f;
        } else {
            // timeout fallback: bit-exact self-warm-up (identical f32 chain)
            HT = valid ? HT0[pix] : 0.0f;
            LT = valid ? LT0[pix] : 0.0f;
            for (int t = 0; t < t0; t += 8) {
                float v[8];
                #pragma unroll
                for (int i = 0; i < 8; ++i) v[i] = xp[(t + i) * HW];
                #pragma unroll
                for (int i = 0; i < 8; ++i) {
                    const float img = v[i];
                    HT = ((img - HT) > 0.0f) ? (HT + dO) : (HT - dC);
                    LT = ((LT - img) > 0.0f) ? (LT - dO) : (LT + dC);
                }
            }
        }
    }

    const bool doOut = (tx >= 1) & (tx <= IN_W) & (ty >= 1) & (ty <= IN_H) & valid;
    const int ym = max(ty - 1, 0);
    const int yp = min(ty + 1, TILE_H - 1);

    for (int tb = t0; tb < t0 + SNAP; tb += BUF) {
        float v[BUF], hot[BUF];
        #pragma unroll
        for (int i = 0; i < BUF; ++i) v[i] = xp[(tb + i) * HW];
        #pragma unroll
        for (int i = 0; i < BUF; ++i) {
            const float img = v[i];
            const float aH = img - HT;
            const float eH = __builtin_amdgcn_exp2f(fmaf(aH, -C1, c0));
            const float hH = __builtin_amdgcn_rcpf(1.0f + eH);
            HT = (aH > 0.0f) ? (HT + dO) : (HT - dC);
            const float aL = LT - img;
            const float eL = __builtin_amdgcn_exp2f(fmaf(aL, -C1, c0));
            const float hL = __builtin_amdgcn_rcpf(1.0f + eL);
            LT = (aL > 0.0f) ? (LT - dO) : (LT + dC);
            hot[i] = valid ? (hH + hL) : 1.0f;
            sm[ty][i][tx] = hot[i];
        }
        __syncthreads();
        #pragma unroll
        for (int i = 0; i < BUF; ++i) {
            const float r0 = sm[ym][i][tx];
            const float r1 = sm[yp][i][tx];
            const float vs = r0 + hot[i] + r1;               // vertical box sum
            const float S  = vs + dpp_from_left(vs) + dpp_from_right(vs);
            float o = fmaf(S, kw, -1.0f);                    // 1 - kw*(9-S) = kw*S - 1
            o = fmaxf(o, 0.0f);
            if (doOut) op[(tb + i) * HW] = o;
        }
        __syncthreads();
    }
}

// ---------------- two-launch fallback (R9-proven) -------------------------
template <int SNAP_>
__global__ __launch_bounds__(256, 1)
void svs_scan(const float* __restrict__ x, const float* __restrict__ params,
              const float* __restrict__ HT0, const float* __restrict__ LT0,
              float2* __restrict__ snap)
{
    constexpr int TEFF_ = T_FRAMES - SNAP_;
    const int pix = (int)blockIdx.x * 256 + (int)threadIdx.x;
    const float dC = params[0];
    const float dO = params[1];

    float HT = HT0[pix];
    float LT = LT0[pix];
    const float* xp = x + pix;

    float va[PRE], vb[PRE];
    #pragma unroll
    for (int i = 0; i < PRE; ++i) va[i] = xp[i * HW];
    __builtin_amdgcn_sched_barrier(0);

    for (int t = 0; t < TEFF_; t += 2 * PRE) {
        #pragma unroll
        for (int i = 0; i < PRE; ++i) vb[i] = xp[(t + PRE + i) * HW];
        __builtin_amdgcn_sched_barrier(0);
        #pragma unroll
        for (int i = 0; i < PRE; ++i) {
            const float img = va[i];
            HT = ((img - HT) > 0.0f) ? (HT + dO) : (HT - dC);
            LT = ((LT - img) > 0.0f) ? (LT - dO) : (LT + dC);
        }
        if (((t + PRE) % SNAP_) == 0) {
            const int k = (t + PRE) / SNAP_ - 1;
            if (k >= 0 && k < T_FRAMES / SNAP_ - 1)
                snap[(size_t)k * HW + pix] = make_float2(HT, LT);
        }
        if (t + 2 * PRE < TEFF_) {
            #pragma unroll
            for (int i = 0; i < PRE; ++i) va[i] = xp[(t + 2 * PRE + i) * HW];
        }
        __builtin_amdgcn_sched_barrier(0);
        #pragma unroll
        for (int i = 0; i < PRE; ++i) {
            const float img = vb[i];
            HT = ((img - HT) > 0.0f) ? (HT + dO) : (HT - dC);
            LT = ((LT - img) > 0.0f) ? (LT - dO) : (LT + dC);
        }
        if (((t + 2 * PRE) % SNAP_) == 0) {
            const int k = (t + 2 * PRE) / SNAP_ - 1;
            if (k < T_FRAMES / SNAP_ - 1)
                snap[(size_t)k * HW + pix] = make_float2(HT, LT);
        }
    }
}

template <int SNAP_>
__global__ __launch_bounds__(256)
void svs_compute(const float* __restrict__ x, const float* __restrict__ params,
                 const float* __restrict__ HT0, const float* __restrict__ LT0,
                 const float* __restrict__ kern, const float2* __restrict__ snap,
                 float* __restrict__ out)
{
    constexpr int TOTAL_ = 120 * (T_FRAMES / SNAP_);
    const int lin = (int)blockIdx.x + 12 * (int)blockIdx.y + 120 * (int)blockIdx.z;
    const int w   = (lin & 7) * (TOTAL_ / 8) + (lin >> 3);
    const int bx  = w % 12;
    const int by  = (w / 12) % 10;
    const int slice = w / 120;

    const int tx = threadIdx.x & 15;
    const int ty = threadIdx.x >> 4;
    const int gx = bx * IN_W + tx - 1;
    const int gy = by * IN_H + ty - 1;
    const int t0 = slice * SNAP_;

    const bool valid = (gx >= 0) & (gx < W_IMG) & (gy >= 0) & (gy < H_IMG);
    const int cx = min(max(gx, 0), W_IMG - 1);
    const int cy = min(max(gy, 0), H_IMG - 1);
    const int pix = cy * W_IMG + cx;

    const float dC   = params[0];
    const float dO   = params[1];
    const float dHot = params[2];
    const float kw   = kern[4];
    const float c0   = dHot * C1;

    float HT, LT;
    if (slice == 0) {
        HT = valid ? HT0[pix] : 0.0f;
        LT = valid ? LT0[pix] : 0.0f;
    } else {
        const float2 s = snap[(size_t)(slice - 1) * HW + pix];
        HT = valid ? s.x : 0.0f;
        LT = valid ? s.y : 0.0f;
    }

    __shared__ float sm[TILE_H][BUF][TILE_W + 1];
    const bool doOut = (tx >= 1) & (tx <= IN_W) & (ty >= 1) & (ty <= IN_H) & valid;
    const int ym = max(ty - 1, 0);
    const int yp = min(ty + 1, TILE_H - 1);
    const float* xp = x + pix;
    float* op = out + pix;

    for (int tb = t0; tb < t0 + SNAP_; tb += BUF) {
        float v[BUF], hot[BUF];
        #pragma unroll
        for (int i = 0; i < BUF; ++i) v[i] = xp[(tb + i) * HW];
        #pragma unroll
        for (int i = 0; i < BUF; ++i) {
            const float img = v[i];
            const float aH = img - HT;
            const float eH = __builtin_amdgcn_exp2f(fmaf(aH, -C1, c0));
            const float hH = __builtin_amdgcn_rcpf(1.0f + eH);
            HT = (aH > 0.0f) ? (HT + dO) : (HT - dC);
            const float aL = LT - img;
            const float eL = __builtin_amdgcn_exp2f(fmaf(aL, -C1, c0));
            const float hL = __builtin_amdgcn_rcpf(1.0f + eL);
            LT = (aL > 0.0f) ? (LT - dO) : (LT + dC);
            hot[i] = valid ? (hH + hL) : 1.0f;
            sm[ty][i][tx] = hot[i];
        }
        __syncthreads();
        #pragma unroll
        for (int i = 0; i < BUF; ++i) {
            const float r0 = sm[ym][i][tx];
            const float r1 = sm[yp][i][tx];
            const float vs = r0 + hot[i] + r1;
            const float S  = vs + dpp_from_left(vs) + dpp_from_right(vs);
            float o = fmaf(S, kw, -1.0f);
            o = fmaxf(o, 0.0f);
            if (doOut) op[(tb + i) * HW] = o;
        }
        __syncthreads();
    }
}

extern "C" void kernel_launch(void* const* d_in, const int* in_sizes, int n_in,
                              void* d_out, int out_size, void* d_ws, size_t ws_size,
                              hipStream_t stream) {
    const float* x      = (const float*)d_in[0];
    const float* params = (const float*)d_in[1];
    const float* HT0p   = (const float*)d_in[2];
    const float* LT0p   = (const float*)d_in[3];
    const float* kern   = (const float*)d_in[4];
    float* out = (float*)d_out;

    if (ws_size >= WS_MERGED) {
        int* flags = (int*)d_ws;
        float2* snap = (float2*)((char*)d_ws + FLAGS_BYTES);
        (void)hipMemsetAsync(d_ws, 0, FLAGS_BYTES, stream);
        svs_pc<<<dim3(SCAN_BLOCKS + COMPUTE_BLOCKS), dim3(256), 0, stream>>>(
            x, params, HT0p, LT0p, kern, snap, flags, out);
    } else if (ws_size >= ws_needed(64)) {
        float2* snap = (float2*)d_ws;
        svs_scan<64><<<dim3(HW / 256), dim3(256), 0, stream>>>(x, params, HT0p, LT0p, snap);
        svs_compute<64><<<dim3(12, 10, T_FRAMES / 64), dim3(256), 0, stream>>>(
            x, params, HT0p, LT0p, kern, snap, out);
    } else if (ws_size >= ws_needed(128)) {
        float2* snap = (float2*)d_ws;
        svs_scan<128><<<dim3(HW / 256), dim3(256), 0, stream>>>(x, params, HT0p, LT0p, snap);
        svs_compute<128><<<dim3(12, 10, T_FRAMES / 128), dim3(256), 0, stream>>>(
            x, params, HT0p, LT0p, kern, snap, out);
    } else {
        svs_compute<2048><<<dim3(12, 10, 1), dim3(256), 0, stream>>>(
            x, params, HT0p, LT0p, kern, (const float2*)d_ws, out);
    }
}

// Round 11
// 187.335 us; speedup vs baseline: 4.7950x; 4.7950x over previous
//
#include <hip/hip_runtime.h>

// SVSAlgorithm: per-pixel sequential threshold recurrence over T frames,
// fused with 3x3 constant-kernel "DiffErosion" conv + relu epilogue.
//
// Two-launch design (kernel-role fusion permanently abandoned: R5/R8/R10
// all collapsed to VGPR=60 / sunk scan loads under one shared regalloc).
//  L1 svs_scan2: 160 blocks x 64 thr, TWO chains/thread via float2 loads ->
//     512B contiguous per wave-instruction (R9's scalar 256B requests at
//     80KB stride capped at ~3.1 TB/s; bytes-per-request is the lever).
//     R9-proven double-buffer shape: PRE=16 float2 (64 data VGPRs), each
//     issue block pinned with sched_barrier(0) (stops compiler load-sinking
//     -- the R5-R8 collapse mechanism), __launch_bounds__(64,1).
//     Snapshots every 64 frames as one float4 (layout == compute's float2).
//     Frames >= 1984 never consumed -> skipped.
//  L2 svs_compute<SNAP=64>: R9-proven body, BUF 8->16 (8 barriers/slice
//     instead of 16; VGPR stays <=64 so 8 blocks/CU is preserved -- the
//     32-wave/CU cliff is at VGPR=64). 16x16 tile (14x14 interior + halo
//     recompute), sigmoid via exp2(fma)+v_rcp, conv == box-sum (all 9
//     weights equal): vertical = 2 LDS reads + own reg, horizontal via DPP
//     row_shr/shl; LDS sm[row][frame][col], row stride BUF*17=272 == 16
//     mod 32 banks -> 2-way max (free). XCD-grouped remap for output-line
//     L2 merging. State updates replicate reference f32 op order exactly.
//  ws ladder: SNAP=64 (5.1MB) -> SNAP=128 (2.4MB) -> single-slice.

#define TILE_W 16
#define TILE_H 16
#define IN_W 14
#define IN_H 14
#define BUF 16       // frames per LDS stage in compute pass
#define PRE2 16      // scan: float2 loads per batch (double buffer)

constexpr int T_FRAMES = 2048;
constexpr int H_IMG = 128;
constexpr int W_IMG = 160;
constexpr int HW = H_IMG * W_IMG;
constexpr int SNAP = 64;
constexpr int TEFF = T_FRAMES - SNAP;            // 1984
constexpr float C1 = 721.3475204444817f;         // 500 * log2(e)

constexpr size_t ws_needed(int snap) {
    return (size_t)(T_FRAMES / snap - 1) * HW * sizeof(float2);
}

__device__ __forceinline__ float dpp_from_left(float v) {   // lane n <- lane n-1 (16-lane rows)
    return __int_as_float(__builtin_amdgcn_update_dpp(0, __float_as_int(v), 0x111, 0xF, 0xF, true));
}
__device__ __forceinline__ float dpp_from_right(float v) {  // lane n <- lane n+1
    return __int_as_float(__builtin_amdgcn_update_dpp(0, __float_as_int(v), 0x101, 0xF, 0xF, true));
}

// ---------------- L1: state-only scan, float2 chains, pinned dbuf ---------
__global__ __launch_bounds__(64, 1)
void svs_scan2(const float* __restrict__ x, const float* __restrict__ params,
               const float* __restrict__ HT0, const float* __restrict__ LT0,
               float4* __restrict__ snap4)
{
    const int pix2 = (int)blockIdx.x * 64 + (int)threadIdx.x;  // chain-pair; 160 blocks
    const float dC = params[0];
    const float dO = params[1];

    const float2 h0 = ((const float2*)HT0)[pix2];
    const float2 l0 = ((const float2*)LT0)[pix2];
    float HTx = h0.x, HTy = h0.y, LTx = l0.x, LTy = l0.y;
    const float2* xp2 = (const float2*)x + pix2;

    float2 va[PRE2], vb[PRE2];
    #pragma unroll
    for (int i = 0; i < PRE2; ++i) va[i] = xp2[i * (HW / 2)];
    __builtin_amdgcn_sched_barrier(0);

    for (int t = 0; t < TEFF; t += 2 * PRE2) {     // 32 frames per iter
        #pragma unroll
        for (int i = 0; i < PRE2; ++i) vb[i] = xp2[(t + PRE2 + i) * (HW / 2)];
        __builtin_amdgcn_sched_barrier(0);
        #pragma unroll
        for (int i = 0; i < PRE2; ++i) {
            const float ix = va[i].x, iy = va[i].y;
            HTx = ((ix - HTx) > 0.0f) ? (HTx + dO) : (HTx - dC);
            LTx = ((LTx - ix) > 0.0f) ? (LTx - dO) : (LTx + dC);
            HTy = ((iy - HTy) > 0.0f) ? (HTy + dO) : (HTy - dC);
            LTy = ((LTy - iy) > 0.0f) ? (LTy - dO) : (LTy + dC);
        }
        if (t + 2 * PRE2 < TEFF) {
            #pragma unroll
            for (int i = 0; i < PRE2; ++i) va[i] = xp2[(t + 2 * PRE2 + i) * (HW / 2)];
        }
        __builtin_amdgcn_sched_barrier(0);
        #pragma unroll
        for (int i = 0; i < PRE2; ++i) {
            const float ix = vb[i].x, iy = vb[i].y;
            HTx = ((ix - HTx) > 0.0f) ? (HTx + dO) : (HTx - dC);
            LTx = ((LTx - ix) > 0.0f) ? (LTx - dO) : (LTx + dC);
            HTy = ((iy - HTy) > 0.0f) ? (HTy + dO) : (HTy - dC);
            LTy = ((LTy - iy) > 0.0f) ? (LTy - dO) : (LTy + dC);
        }
        // state = after frame t+31; snapshot when (t+32) is a SNAP boundary
        if (((t + 2 * PRE2) & (SNAP - 1)) == 0) {
            const int k = (t + 2 * PRE2) / SNAP - 1;      // 0..30
            if (k < T_FRAMES / SNAP - 1)
                snap4[(size_t)k * (HW / 2) + pix2] = make_float4(HTx, LTx, HTy, LTy);
        }
    }
}

// ---------------- L2: per-slice fused compute -----------------------------
template <int SNAP_>
__global__ __launch_bounds__(256)
void svs_compute(const float* __restrict__ x, const float* __restrict__ params,
                 const float* __restrict__ HT0, const float* __restrict__ LT0,
                 const float* __restrict__ kern, const float2* __restrict__ snap,
                 float* __restrict__ out)
{
    constexpr int TOTAL_ = 120 * (T_FRAMES / SNAP_);
    // XCD-grouped remap: contiguous chunks of linear block id per XCD so
    // adjacent-bx tiles (sharing output cache lines) land on one XCD L2.
    const int lin = (int)blockIdx.x + 12 * (int)blockIdx.y + 120 * (int)blockIdx.z;
    const int w   = (lin & 7) * (TOTAL_ / 8) + (lin >> 3);   // TOTAL_%8==0 -> bijective
    const int bx  = w % 12;
    const int by  = (w / 12) % 10;
    const int slice = w / 120;

    const int tx = threadIdx.x & 15;
    const int ty = threadIdx.x >> 4;
    const int gx = bx * IN_W + tx - 1;
    const int gy = by * IN_H + ty - 1;
    const int t0 = slice * SNAP_;

    const bool valid = (gx >= 0) & (gx < W_IMG) & (gy >= 0) & (gy < H_IMG);
    const int cx = min(max(gx, 0), W_IMG - 1);
    const int cy = min(max(gy, 0), H_IMG - 1);
    const int pix = cy * W_IMG + cx;

    const float dC   = params[0];
    const float dO   = params[1];
    const float dHot = params[2];
    const float kw   = kern[4];        // all 9 weights equal (2/9)
    const float c0   = dHot * C1;      // exp2 arg = fma(a, -C1, c0)

    float HT, LT;
    if (slice == 0) {
        HT = valid ? HT0[pix] : 0.0f;
        LT = valid ? LT0[pix] : 0.0f;
    } else {
        const float2 s = snap[(size_t)(slice - 1) * HW + pix];
        HT = valid ? s.x : 0.0f;
        LT = valid ? s.y : 0.0f;
    }

    // sm[row][frame][col]: row stride BUF*17=272 floats == 16 mod 32 banks ->
    // wave's 4 row-clusters at bank shifts {0,16,0,16}: 2-way max (free).
    __shared__ float sm[TILE_H][BUF][TILE_W + 1];

    const bool doOut = (tx >= 1) & (tx <= IN_W) & (ty >= 1) & (ty <= IN_H) & valid;
    const int ym = max(ty - 1, 0);
    const int yp = min(ty + 1, TILE_H - 1);
    const float* xp = x + pix;
    float* op = out + pix;

    for (int tb = t0; tb < t0 + SNAP_; tb += BUF) {
        float v[BUF], hot[BUF];
        #pragma unroll
        for (int i = 0; i < BUF; ++i) v[i] = xp[(tb + i) * HW];
        #pragma unroll
        for (int i = 0; i < BUF; ++i) {
            const float img = v[i];
            const float aH = img - HT;
            const float eH = __builtin_amdgcn_exp2f(fmaf(aH, -C1, c0));
            const float hH = __builtin_amdgcn_rcpf(1.0f + eH);
            HT = (aH > 0.0f) ? (HT + dO) : (HT - dC);
            const float aL = LT - img;
            const float eL = __builtin_amdgcn_exp2f(fmaf(aL, -C1, c0));
            const float hL = __builtin_amdgcn_rcpf(1.0f + eL);
            LT = (aL > 0.0f) ? (LT - dO) : (LT + dC);
            hot[i] = valid ? (hH + hL) : 1.0f;
            sm[ty][i][tx] = hot[i];
        }
        __syncthreads();
        #pragma unroll
        for (int i = 0; i < BUF; ++i) {
            const float r0 = sm[ym][i][tx];
            const float r1 = sm[yp][i][tx];
            const float vs = r0 + hot[i] + r1;               // vertical box sum
            const float S  = vs + dpp_from_left(vs) + dpp_from_right(vs);
            float o = fmaf(S, kw, -1.0f);                    // 1 - kw*(9-S) = kw*S - 1
            o = fmaxf(o, 0.0f);
            if (doOut) op[(tb + i) * HW] = o;
        }
        __syncthreads();
    }
}

// ---------------- scalar scan fallback (SNAP=128 ladder) ------------------
template <int SNAP_>
__global__ __launch_bounds__(256, 1)
void svs_scan(const float* __restrict__ x, const float* __restrict__ params,
              const float* __restrict__ HT0, const float* __restrict__ LT0,
              float2* __restrict__ snap)
{
    constexpr int PRE = 32;
    constexpr int TEFF_ = T_FRAMES - SNAP_;
    const int pix = (int)blockIdx.x * 256 + (int)threadIdx.x;
    const float dC = params[0];
    const float dO = params[1];

    float HT = HT0[pix];
    float LT = LT0[pix];
    const float* xp = x + pix;

    float va[PRE], vb[PRE];
    #pragma unroll
    for (int i = 0; i < PRE; ++i) va[i] = xp[i * HW];
    __builtin_amdgcn_sched_barrier(0);

    for (int t = 0; t < TEFF_; t += 2 * PRE) {
        #pragma unroll
        for (int i = 0; i < PRE; ++i) vb[i] = xp[(t + PRE + i) * HW];
        __builtin_amdgcn_sched_barrier(0);
        #pragma unroll
        for (int i = 0; i < PRE; ++i) {
            const float img = va[i];
            HT = ((img - HT) > 0.0f) ? (HT + dO) : (HT - dC);
            LT = ((LT - img) > 0.0f) ? (LT - dO) : (LT + dC);
        }
        if (((t + PRE) % SNAP_) == 0) {
            const int k = (t + PRE) / SNAP_ - 1;
            if (k >= 0 && k < T_FRAMES / SNAP_ - 1)
                snap[(size_t)k * HW + pix] = make_float2(HT, LT);
        }
        if (t + 2 * PRE < TEFF_) {
            #pragma unroll
            for (int i = 0; i < PRE; ++i) va[i] = xp[(t + 2 * PRE + i) * HW];
        }
        __builtin_amdgcn_sched_barrier(0);
        #pragma unroll
        for (int i = 0; i < PRE; ++i) {
            const float img = vb[i];
            HT = ((img - HT) > 0.0f) ? (HT + dO) : (HT - dC);
            LT = ((LT - img) > 0.0f) ? (LT - dO) : (LT + dC);
        }
        if (((t + 2 * PRE) % SNAP_) == 0) {
            const int k = (t + 2 * PRE) / SNAP_ - 1;
            if (k < T_FRAMES / SNAP_ - 1)
                snap[(size_t)k * HW + pix] = make_float2(HT, LT);
        }
    }
}

extern "C" void kernel_launch(void* const* d_in, const int* in_sizes, int n_in,
                              void* d_out, int out_size, void* d_ws, size_t ws_size,
                              hipStream_t stream) {
    const float* x      = (const float*)d_in[0];
    const float* params = (const float*)d_in[1];
    const float* HT0p   = (const float*)d_in[2];
    const float* LT0p   = (const float*)d_in[3];
    const float* kern   = (const float*)d_in[4];
    float* out = (float*)d_out;

    if (ws_size >= ws_needed(64)) {
        svs_scan2<<<dim3(HW / 128), dim3(64), 0, stream>>>(
            x, params, HT0p, LT0p, (float4*)d_ws);
        svs_compute<64><<<dim3(12, 10, T_FRAMES / 64), dim3(256), 0, stream>>>(
            x, params, HT0p, LT0p, kern, (const float2*)d_ws, out);
    } else if (ws_size >= ws_needed(128)) {
        float2* snap = (float2*)d_ws;
        svs_scan<128><<<dim3(HW / 256), dim3(256), 0, stream>>>(x, params, HT0p, LT0p, snap);
        svs_compute<128><<<dim3(12, 10, T_FRAMES / 128), dim3(256), 0, stream>>>(
            x, params, HT0p, LT0p, kern, snap, out);
    } else {
        svs_compute<2048><<<dim3(12, 10, 1), dim3(256), 0, stream>>>(
            x, params, HT0p, LT0p, kern, (const float2*)d_ws, out);
    }
}

// Round 12
// 168.277 us; speedup vs baseline: 5.3381x; 1.1133x over previous
//
#include <hip/hip_runtime.h>

// SVSAlgorithm: per-pixel sequential threshold recurrence over T frames,
// fused with 3x3 constant-kernel "DiffErosion" conv + relu epilogue.
//
// Two-launch design. Closed dead-ends (do not revisit): kernel-role fusion
// (R5/R8/R10: shared regalloc collapses the scan pipeline to VGPR=60);
// float2 scan (R7/R11: compiler won't keep 2 float2 buffers live + halves
// wave count). Proven parts ledger: scalar pinned scan ~50us (R9);
// compute<64> BUF=16 ~90us (R11).
//  L1 svs_scan<64>: R9-proven verbatim. 80 blocks x 256 thr, 1 chain/thr,
//     2x32 double-buffered prefetch, sched_barrier(0) pins each issue block
//     (stops compiler load-sinking), __launch_bounds__(256,1). Skips frames
//     >= 1984 (never consumed). Snapshots (HT,LT) every 64 frames -> d_ws.
//  L2 svs_compute<64>: R11 body + T14 async-stage split: stage tb issues
//     stage tb+BUF's 16 x-loads FIRST (pinned), so their latency hides
//     under sigmoid+conv+2 barriers; vmcnt wait lands at the register
//     rotation after the 2nd barrier. VGPR ~52 < 64 cliff (8 blocks/CU).
//     Sigmoid via exp2(fma)+v_rcp; conv == box-sum (all 9 weights equal):
//     vertical = 2 LDS reads + own reg, horizontal via DPP row_shr/shl;
//     LDS sm[row][frame][col] (row stride 272 == 16 mod 32 banks -> 2-way
//     max, free). XCD-grouped remap for output-line L2 merging.
//     State updates replicate reference f32 op order exactly.
//  ws ladder: SNAP=64 (5.1MB) -> SNAP=128 (2.4MB) -> single-slice.

#define TILE_W 16
#define TILE_H 16
#define IN_W 14
#define IN_H 14
#define BUF 16       // frames per LDS stage in compute pass
#define PRE 32       // scan prefetch half-depth (double buffer)

constexpr int T_FRAMES = 2048;
constexpr int H_IMG = 128;
constexpr int W_IMG = 160;
constexpr int HW = H_IMG * W_IMG;
constexpr float C1 = 721.3475204444817f;         // 500 * log2(e)

constexpr size_t ws_needed(int snap) {
    return (size_t)(T_FRAMES / snap - 1) * HW * sizeof(float2);
}

__device__ __forceinline__ float dpp_from_left(float v) {   // lane n <- lane n-1 (16-lane rows)
    return __int_as_float(__builtin_amdgcn_update_dpp(0, __float_as_int(v), 0x111, 0xF, 0xF, true));
}
__device__ __forceinline__ float dpp_from_right(float v) {  // lane n <- lane n+1
    return __int_as_float(__builtin_amdgcn_update_dpp(0, __float_as_int(v), 0x101, 0xF, 0xF, true));
}

// ---------------- L1: state-only scan (R9-proven, scalar, pinned) ---------
template <int SNAP_>
__global__ __launch_bounds__(256, 1)
void svs_scan(const float* __restrict__ x, const float* __restrict__ params,
              const float* __restrict__ HT0, const float* __restrict__ LT0,
              float2* __restrict__ snap)
{
    constexpr int TEFF_ = T_FRAMES - SNAP_;      // tail frames never consumed
    const int pix = (int)blockIdx.x * 256 + (int)threadIdx.x;  // 80 blocks
    const float dC = params[0];
    const float dO = params[1];

    float HT = HT0[pix];
    float LT = LT0[pix];
    const float* xp = x + pix;

    float va[PRE], vb[PRE];
    #pragma unroll
    for (int i = 0; i < PRE; ++i) va[i] = xp[i * HW];
    __builtin_amdgcn_sched_barrier(0);

    for (int t = 0; t < TEFF_; t += 2 * PRE) {
        #pragma unroll
        for (int i = 0; i < PRE; ++i) vb[i] = xp[(t + PRE + i) * HW];
        __builtin_amdgcn_sched_barrier(0);
        #pragma unroll
        for (int i = 0; i < PRE; ++i) {
            const float img = va[i];
            HT = ((img - HT) > 0.0f) ? (HT + dO) : (HT - dC);
            LT = ((LT - img) > 0.0f) ? (LT - dO) : (LT + dC);
        }
        if (((t + PRE) % SNAP_) == 0) {
            const int k = (t + PRE) / SNAP_ - 1;
            if (k >= 0 && k < T_FRAMES / SNAP_ - 1)
                snap[(size_t)k * HW + pix] = make_float2(HT, LT);
        }
        if (t + 2 * PRE < TEFF_) {
            #pragma unroll
            for (int i = 0; i < PRE; ++i) va[i] = xp[(t + 2 * PRE + i) * HW];
        }
        __builtin_amdgcn_sched_barrier(0);
        #pragma unroll
        for (int i = 0; i < PRE; ++i) {
            const float img = vb[i];
            HT = ((img - HT) > 0.0f) ? (HT + dO) : (HT - dC);
            LT = ((LT - img) > 0.0f) ? (LT - dO) : (LT + dC);
        }
        if (((t + 2 * PRE) % SNAP_) == 0) {
            const int k = (t + 2 * PRE) / SNAP_ - 1;
            if (k < T_FRAMES / SNAP_ - 1)
                snap[(size_t)k * HW + pix] = make_float2(HT, LT);
        }
    }
}

// ---------------- L2: per-slice fused compute + async-stage split ---------
template <int SNAP_>
__global__ __launch_bounds__(256)
void svs_compute(const float* __restrict__ x, const float* __restrict__ params,
                 const float* __restrict__ HT0, const float* __restrict__ LT0,
                 const float* __restrict__ kern, const float2* __restrict__ snap,
                 float* __restrict__ out)
{
    constexpr int TOTAL_ = 120 * (T_FRAMES / SNAP_);
    // XCD-grouped remap: contiguous chunks of linear block id per XCD so
    // adjacent-bx tiles (sharing output cache lines) land on one XCD L2.
    const int lin = (int)blockIdx.x + 12 * (int)blockIdx.y + 120 * (int)blockIdx.z;
    const int w   = (lin & 7) * (TOTAL_ / 8) + (lin >> 3);   // TOTAL_%8==0 -> bijective
    const int bx  = w % 12;
    const int by  = (w / 12) % 10;
    const int slice = w / 120;

    const int tx = threadIdx.x & 15;
    const int ty = threadIdx.x >> 4;
    const int gx = bx * IN_W + tx - 1;
    const int gy = by * IN_H + ty - 1;
    const int t0 = slice * SNAP_;

    const bool valid = (gx >= 0) & (gx < W_IMG) & (gy >= 0) & (gy < H_IMG);
    const int cx = min(max(gx, 0), W_IMG - 1);
    const int cy = min(max(gy, 0), H_IMG - 1);
    const int pix = cy * W_IMG + cx;

    const float dC   = params[0];
    const float dO   = params[1];
    const float dHot = params[2];
    const float kw   = kern[4];        // all 9 weights equal (2/9)
    const float c0   = dHot * C1;      // exp2 arg = fma(a, -C1, c0)

    float HT, LT;
    if (slice == 0) {
        HT = valid ? HT0[pix] : 0.0f;
        LT = valid ? LT0[pix] : 0.0f;
    } else {
        const float2 s = snap[(size_t)(slice - 1) * HW + pix];
        HT = valid ? s.x : 0.0f;
        LT = valid ? s.y : 0.0f;
    }

    // sm[row][frame][col]: row stride BUF*17=272 floats == 16 mod 32 banks ->
    // wave's 4 row-clusters at bank shifts {0,16,0,16}: 2-way max (free).
    __shared__ float sm[TILE_H][BUF][TILE_W + 1];

    const bool doOut = (tx >= 1) & (tx <= IN_W) & (ty >= 1) & (ty <= IN_H) & valid;
    const int ym = max(ty - 1, 0);
    const int yp = min(ty + 1, TILE_H - 1);
    const float* xp = x + pix;
    float* op = out + pix;

    float v[BUF], vn[BUF], hot[BUF];
    #pragma unroll
    for (int i = 0; i < BUF; ++i) v[i] = xp[(t0 + i) * HW];

    for (int tb = t0; tb < t0 + SNAP_; tb += BUF) {
        const bool more = (tb + BUF) < (t0 + SNAP_);
        // T14 async-stage split: issue next stage's loads FIRST (pinned so
        // the scheduler can't sink them); their wait lands at the rotation
        // after the 2nd barrier -> latency hides under sigmoid+conv.
        if (more) {
            #pragma unroll
            for (int i = 0; i < BUF; ++i) vn[i] = xp[(tb + BUF + i) * HW];
        }
        __builtin_amdgcn_sched_barrier(0);
        #pragma unroll
        for (int i = 0; i < BUF; ++i) {
            const float img = v[i];
            const float aH = img - HT;
            const float eH = __builtin_amdgcn_exp2f(fmaf(aH, -C1, c0));
            const float hH = __builtin_amdgcn_rcpf(1.0f + eH);
            HT = (aH > 0.0f) ? (HT + dO) : (HT - dC);
            const float aL = LT - img;
            const float eL = __builtin_amdgcn_exp2f(fmaf(aL, -C1, c0));
            const float hL = __builtin_amdgcn_rcpf(1.0f + eL);
            LT = (aL > 0.0f) ? (LT - dO) : (LT + dC);
            hot[i] = valid ? (hH + hL) : 1.0f;
            sm[ty][i][tx] = hot[i];
        }
        __syncthreads();
        #pragma unroll
        for (int i = 0; i < BUF; ++i) {
            const float r0 = sm[ym][i][tx];
            const float r1 = sm[yp][i][tx];
            const float vs = r0 + hot[i] + r1;               // vertical box sum
            const float S  = vs + dpp_from_left(vs) + dpp_from_right(vs);
            float o = fmaf(S, kw, -1.0f);                    // 1 - kw*(9-S) = kw*S - 1
            o = fmaxf(o, 0.0f);
            if (doOut) op[(tb + i) * HW] = o;
        }
        __syncthreads();
        if (more) {
            #pragma unroll
            for (int i = 0; i < BUF; ++i) v[i] = vn[i];
        }
    }
}

extern "C" void kernel_launch(void* const* d_in, const int* in_sizes, int n_in,
                              void* d_out, int out_size, void* d_ws, size_t ws_size,
                              hipStream_t stream) {
    const float* x      = (const float*)d_in[0];
    const float* params = (const float*)d_in[1];
    const float* HT0p   = (const float*)d_in[2];
    const float* LT0p   = (const float*)d_in[3];
    const float* kern   = (const float*)d_in[4];
    float* out = (float*)d_out;

    if (ws_size >= ws_needed(64)) {
        float2* snap = (float2*)d_ws;
        svs_scan<64><<<dim3(HW / 256), dim3(256), 0, stream>>>(x, params, HT0p, LT0p, snap);
        svs_compute<64><<<dim3(12, 10, T_FRAMES / 64), dim3(256), 0, stream>>>(
            x, params, HT0p, LT0p, kern, snap, out);
    } else if (ws_size >= ws_needed(128)) {
        float2* snap = (float2*)d_ws;
        svs_scan<128><<<dim3(HW / 256), dim3(256), 0, stream>>>(x, params, HT0p, LT0p, snap);
        svs_compute<128><<<dim3(12, 10, T_FRAMES / 128), dim3(256), 0, stream>>>(
            x, params, HT0p, LT0p, kern, snap, out);
    } else {
        svs_compute<2048><<<dim3(12, 10, 1), dim3(256), 0, stream>>>(
            x, params, HT0p, LT0p, kern, (const float2*)d_ws, out);
    }
}